// Round 2
// baseline (209.476 us; speedup 1.0000x reference)
//
#include <hip/hip_runtime.h>

// ---------------------------------------------------------------------------
//   x: (32, 512, 128) fp32 -> rows r = b*128 + c, 4096 rows
//   h[r][n2] = sum_l xt[r][l] * W2[n2][l] + b2[n2],  W2 = lin2_w @ lin1_w
//   out[r][t] = h[r][t] + mamba1(h[r][:])[t]        (x1 branch is exactly 0)
// R8 structure: 2 dispatches.
//   w2t_all  (full-K 32x32 tiles + b2 blocks, 136 blk)
//   fused_h_mamba (512 blk x 256 thr, 2/CU, 8 rows/block):
//     GEMM phase with BALANCED wave tile (16-row-group x 64-col per wave,
//     0.5 B/FMA LDS traffic instead of 2 B/FMA) writing h into LDS, then the
//     verified 8-row scan (identical to old mamba_res phases 1-3).
// ---------------------------------------------------------------------------

__device__ __forceinline__ float rcp_f(float x) { return __builtin_amdgcn_rcpf(x); }
__device__ __forceinline__ float silu_f(float x) {
    return x * rcp_f(1.0f + __expf(-x));
}
__device__ __forceinline__ float softplus_f(float x) {
    return fmaxf(x, 0.0f) + __logf(1.0f + __expf(-fabsf(x)));
}

__device__ __forceinline__ unsigned f2_to_h2(float a, float b) {
    _Float16 ha = (_Float16)a, hb = (_Float16)b;
    unsigned short ua = __builtin_bit_cast(unsigned short, ha);
    unsigned short ub = __builtin_bit_cast(unsigned short, hb);
    return (unsigned)ua | ((unsigned)ub << 16);
}
__device__ __forceinline__ float h16_to_f(unsigned u) {
    unsigned short s = (unsigned short)u;
    _Float16 h = __builtin_bit_cast(_Float16, s);
    return (float)h;
}

// DPP row_shr add (rows of 16 lanes); bound_ctrl=1 -> out-of-row reads 0.
#define DPP_ADD(s, ctrl)                                                       \
    (s) += __int_as_float(__builtin_amdgcn_update_dpp(                         \
        0, __float_as_int(s), (ctrl), 0xf, 0xf, true))

// ---------------------------------------------------------------------------
// Kernel A: bid<128: W2T[l*256+n2] = sum_k lin2[n2][k]*lin1[k][l], full K=512,
// 32x32 output tile per block.  bid>=128: b2 = lin2_w@lin1_b + lin2_b.
// ---------------------------------------------------------------------------
__global__ __launch_bounds__(256)
void w2t_all(const float* __restrict__ A,    // lin2_w (256,512) [m][k]
             const float* __restrict__ B,    // lin1_w (512,512) [k][n]
             const float* __restrict__ lin1_b,
             const float* __restrict__ lin2_b,
             float* __restrict__ W2T, float* __restrict__ b2) {
    __shared__ float As[64][34];
    __shared__ float Bs[64][36];
    __shared__ float red[8][33];
    const int tid = threadIdx.x;
    const int bid = blockIdx.x;
    if (bid < 128) {
        const int m0 = (bid & 7) * 32;
        const int n0 = (bid >> 3) * 32;
        const int tr = tid & 15;
        const int tc = tid >> 4;
        const int ma  = tid >> 3;
        const int kqa = tid & 7;
        const int kb  = tid >> 2;
        const int nqb = tid & 3;
        float acc00 = 0.f, acc01 = 0.f, acc10 = 0.f, acc11 = 0.f;

        for (int k0 = 0; k0 < 512; k0 += 64) {
            float4 a0 = *(const float4*)&A[(m0 + ma) * 512 + k0 + kqa * 8];
            float4 a1 = *(const float4*)&A[(m0 + ma) * 512 + k0 + kqa * 8 + 4];
            As[kqa * 8 + 0][ma] = a0.x;
            As[kqa * 8 + 1][ma] = a0.y;
            As[kqa * 8 + 2][ma] = a0.z;
            As[kqa * 8 + 3][ma] = a0.w;
            As[kqa * 8 + 4][ma] = a1.x;
            As[kqa * 8 + 5][ma] = a1.y;
            As[kqa * 8 + 6][ma] = a1.z;
            As[kqa * 8 + 7][ma] = a1.w;
            float4 b0 = *(const float4*)&B[(k0 + kb) * 512 + n0 + nqb * 8];
            float4 b1 = *(const float4*)&B[(k0 + kb) * 512 + n0 + nqb * 8 + 4];
            *(float4*)&Bs[kb][nqb * 8]     = b0;
            *(float4*)&Bs[kb][nqb * 8 + 4] = b1;
            __syncthreads();
#pragma unroll 16
            for (int kk = 0; kk < 64; ++kk) {
                float2 av = *(const float2*)&As[kk][tr * 2];
                float2 bv = *(const float2*)&Bs[kk][tc * 2];
                acc00 = fmaf(av.x, bv.x, acc00);
                acc01 = fmaf(av.x, bv.y, acc01);
                acc10 = fmaf(av.y, bv.x, acc10);
                acc11 = fmaf(av.y, bv.y, acc11);
            }
            __syncthreads();
        }
        const int m = m0 + tr * 2;
        const int nn = n0 + tc * 2;
        W2T[nn * 256 + m]           = acc00;
        W2T[nn * 256 + m + 1]       = acc10;
        W2T[(nn + 1) * 256 + m]     = acc01;
        W2T[(nn + 1) * 256 + m + 1] = acc11;
    } else {
        const int np = tid & 31;
        const int ks = tid >> 5;
        const int n = (bid - 128) * 32 + np;
        float acc = 0.f;
#pragma unroll 16
        for (int k = ks * 64; k < ks * 64 + 64; k += 4) {
            float4 w  = *(const float4*)&A[n * 512 + k];
            float4 bb = *(const float4*)&lin1_b[k];
            acc += w.x * bb.x + w.y * bb.y + w.z * bb.z + w.w * bb.w;
        }
        red[ks][np] = acc;
        __syncthreads();
        if (ks == 0) {
            float s = red[0][np] + red[1][np] + red[2][np] + red[3][np] +
                      red[4][np] + red[5][np] + red[6][np] + red[7][np];
            b2[n] = s + lin2_b[n];
        }
    }
}

// ---------------------------------------------------------------------------
// Kernel B: 512 blocks x 256 threads, 8 rows/block, ~50 KB LDS -> 2 blocks/CU.
//   GEMM phase: h[8][256] = xt[r0..r0+7][0..511] @ W2T + b2 into LDS.
//     W2T streamed in 32-l chunks (32 KB), register double-buffered.
//     Wave tile: all 8 rows x 64 cols (wave w owns cols w*64..w*64+63);
//     lane (g = lane>>4, c = lane&15) computes rows {2g,2g+1} x cols
//     {w*64+4c..+3}.  Per l: ds_read_b64 x-pair (4 addrs/wave, 32 B) +
//     ds_read_b128 W2T (16 addrs, 256 B, 2-way) + 8 FMA  => ~0.56 B/FMA.
//   Scan phase: byte-identical to the verified 8-row mamba_res (phases 1-3).
//     arrP (16 KB) aliases the dead w2c chunk buffer (32 KB).
// ---------------------------------------------------------------------------
__global__ __launch_bounds__(256, 2)
void fused_h_mamba(const float* __restrict__ x, const float* __restrict__ W2T,
                   const float* __restrict__ b2, float* __restrict__ out,
                   const float* __restrict__ in_w, const float* __restrict__ conv_w,
                   const float* __restrict__ conv_b, const float* __restrict__ xproj,
                   const float* __restrict__ dt_w, const float* __restrict__ dt_b,
                   const float* __restrict__ A_log, const float* __restrict__ Dp,
                   const float* __restrict__ out_w) {
    __shared__ __align__(16) float smem2[8 * 512 + 64];   // 16.6 KB: h, then Sbuf
    __shared__ __align__(16) char  ubuf[32 * 256 * 4];    // 32 KB: w2c -> arrP
    __shared__ __align__(16) float xs[32 * 8];            // 1 KB

    float* w2c  = (float*)ubuf;
    uint2* arrP = (uint2*)ubuf;

    const int tid = threadIdx.x;

    // ---------------- GEMM: h = xt_block @ W2T + b2 ----------------
    {
        const int lane = tid & 63;
        const int wave = tid >> 6;               // 0..3
        const int g    = lane >> 4;              // rows 2g, 2g+1
        const int cc   = wave * 64 + (lane & 15) * 4;  // col base
        const int bb   = (int)blockIdx.x >> 4;
        const int c0   = ((int)blockIdx.x & 15) * 8;
        const float* xbase = x + bb * 65536 + c0;
        const int xl = tid >> 3;                 // 0..31 (chunk-local l)
        const int xc = tid & 7;                  // row (c) index

        float acc[2][4] = {{0.f, 0.f, 0.f, 0.f}, {0.f, 0.f, 0.f, 0.f}};
        float4 wreg[8];
        float  xreg;
        {
            const float4* ws4 = (const float4*)W2T;
#pragma unroll
            for (int q = 0; q < 8; ++q) wreg[q] = ws4[tid + q * 256];
            xreg = xbase[xl * 128 + xc];
        }
        for (int ch = 0; ch < 16; ++ch) {
            xs[xl * 8 + xc] = xreg;
            {
                float4* d4 = (float4*)w2c;
#pragma unroll
                for (int q = 0; q < 8; ++q) d4[tid + q * 256] = wreg[q];
            }
            __syncthreads();
            if (ch < 15) {
                const float4* ws4 = (const float4*)(W2T + (ch + 1) * 8192);
#pragma unroll
                for (int q = 0; q < 8; ++q) wreg[q] = ws4[tid + q * 256];
                xreg = xbase[((ch + 1) * 32 + xl) * 128 + xc];
            }
#pragma unroll 8
            for (int l = 0; l < 32; ++l) {
                const float2 xa = *(const float2*)&xs[l * 8 + g * 2];
                const float4 wv = *(const float4*)&w2c[l * 256 + cc];
                acc[0][0] = fmaf(xa.x, wv.x, acc[0][0]);
                acc[0][1] = fmaf(xa.x, wv.y, acc[0][1]);
                acc[0][2] = fmaf(xa.x, wv.z, acc[0][2]);
                acc[0][3] = fmaf(xa.x, wv.w, acc[0][3]);
                acc[1][0] = fmaf(xa.y, wv.x, acc[1][0]);
                acc[1][1] = fmaf(xa.y, wv.y, acc[1][1]);
                acc[1][2] = fmaf(xa.y, wv.z, acc[1][2]);
                acc[1][3] = fmaf(xa.y, wv.w, acc[1][3]);
            }
            __syncthreads();
        }
        const float4 bias = *(const float4*)&b2[cc];
#pragma unroll
        for (int i = 0; i < 2; ++i) {
            float4 hv = make_float4(acc[i][0] + bias.x, acc[i][1] + bias.y,
                                    acc[i][2] + bias.z, acc[i][3] + bias.w);
            *(float4*)&smem2[(2 * g + i) * 256 + cc] = hv;
        }
    }

    // ---------------- mamba1 + residual (verified 8-row structure) ----------
    const int r0 = blockIdx.x * 8;
    const int row  = tid >> 5;   // 0..7
    const int lane = tid & 31;
    const int d    = lane >> 4;
    const int n    = lane & 15;

    const float iw0 = in_w[0], iw1 = in_w[1], iw2 = in_w[2], iw3 = in_w[3];
    const float g00 = iw0 * conv_w[0], g01 = iw0 * conv_w[1];
    const float g02 = iw0 * conv_w[2], g03 = iw0 * conv_w[3];
    const float g10 = iw1 * conv_w[4], g11 = iw1 * conv_w[5];
    const float g12 = iw1 * conv_w[6], g13 = iw1 * conv_w[7];
    const float cb0 = conv_b[0], cb1 = conv_b[1];
    const float xp00 = xproj[0], xp01 = xproj[1];
    const float dtw0 = dt_w[0], dtw1 = dt_w[1];
    const float dtb0 = dt_b[0], dtb1 = dt_b[1];
    const float D0 = Dp[0], D1 = Dp[1];
    const float ow0 = out_w[0], ow1 = out_w[1];

    __syncthreads();  // h visible to all waves; w2c dead -> arrP may be written

    // phase 1: per-t precompute; pack params to 4xfp16; keep w/base in regs
    float w0a[8], w1a[8], basea[8];
#pragma unroll
    for (int j = 0; j < 8; ++j) {
        const int t = lane + 32 * j;
        const float* u = &smem2[row * 256];
        const float u0 = u[t];
        const int i1 = (t >= 1) ? t - 1 : 0;
        const int i2 = (t >= 2) ? t - 2 : 0;
        const int i3 = (t >= 3) ? t - 3 : 0;
        float um1 = u[i1]; um1 = (t >= 1) ? um1 : 0.f;
        float um2 = u[i2]; um2 = (t >= 2) ? um2 : 0.f;
        float um3 = u[i3]; um3 = (t >= 3) ? um3 : 0.f;

        const float p0 = fmaf(g03, u0, fmaf(g02, um1, fmaf(g01, um2, fmaf(g00, um3, cb0))));
        const float p1 = fmaf(g13, u0, fmaf(g12, um1, fmaf(g11, um2, fmaf(g10, um3, cb1))));
        const float xc0 = silu_f(p0);
        const float xc1 = silu_f(p1);
        const float dbc0 = fmaf(xp01, xc1, xp00 * xc0);
        const float dt0 = softplus_f(fmaf(dbc0, dtw0, dtb0));
        const float dt1 = softplus_f(fmaf(dbc0, dtw1, dtb1));
        const float w0 = silu_f(u0 * iw2) * ow0;
        const float w1 = silu_f(u0 * iw3) * ow1;
        w0a[j] = w0;
        w1a[j] = w1;
        basea[j] = fmaf(xc1 * D1, w1, fmaf(xc0 * D0, w0, u0));
        arrP[row * 256 + t] = make_uint2(f2_to_h2(xc0, xc1), f2_to_h2(dt0, dt1));
    }
    __syncthreads();  // arrP ready; smem2 reused as Sbuf (+trash tail)

    // phase 2: sequential scan; lane owns state (d, n)
    const float a_dn = -__expf(A_log[d * 16 + n]);
    const float bn0 = xproj[(1 + n) * 2 + 0];
    const float bn1 = xproj[(1 + n) * 2 + 1];
    const float cn0 = xproj[(17 + n) * 2 + 0];
    const float cn1 = xproj[(17 + n) * 2 + 1];
    const bool is_writer = ((lane & 15) == 15);
    const int dsh = d * 16;  // fp16 select shift for dt_d
    int addr = is_writer ? (row * 512 + d) : (4096 + (tid & 63));
    const int astep = is_writer ? 2 : 0;
    float hstate = 0.f;

#pragma unroll 8
    for (int t = 0; t < 256; ++t) {
        const uint2 P = arrP[row * 256 + t];  // {h2(xc0,xc1), h2(dt0,dt1)}
        const float xc0 = h16_to_f(P.x);
        const float xc1 = h16_to_f(P.x >> 16);
        const float dtd = h16_to_f(P.y >> dsh);
        const float xcd = d ? xc1 : xc0;
        const float bm = fmaf(bn1, xc1, bn0 * xc0);
        const float cm = fmaf(cn1, xc1, cn0 * xc0);
        const float dA = __expf(dtd * a_dn);
        hstate = fmaf(dA, hstate, dtd * xcd * bm);
        float s = hstate * cm;
        DPP_ADD(s, 0x111);  // row_shr:1
        DPP_ADD(s, 0x112);  // row_shr:2
        DPP_ADD(s, 0x114);  // row_shr:4
        DPP_ADD(s, 0x118);  // row_shr:8 -> lane15 of each 16-row has S_d
        smem2[addr] = s;    // unconditional (trash slot for non-writers)
        addr += astep;
    }
    __syncthreads();

    // phase 3: y = base + w0*S0 + w1*S1, coalesced stores
    float* orow = out + (r0 + row) * 256;
#pragma unroll
    for (int j = 0; j < 8; ++j) {
        const int t = lane + 32 * j;
        const float2 S = *(const float2*)&smem2[((row * 256 + t) << 1)];
        orow[t] = fmaf(w1a[j], S.y, fmaf(w0a[j], S.x, basea[j]));
    }
}

// ---------------------------------------------------------------------------
extern "C" void kernel_launch(void* const* d_in, const int* in_sizes, int n_in,
                              void* d_out, int out_size, void* d_ws, size_t ws_size,
                              hipStream_t stream) {
    const float* x      = (const float*)d_in[0];
    const float* lin1_w = (const float*)d_in[1];
    const float* lin1_b = (const float*)d_in[2];
    const float* lin2_w = (const float*)d_in[3];
    const float* lin2_b = (const float*)d_in[4];
    const float* m1_in_w   = (const float*)d_in[5];
    const float* m1_conv_w = (const float*)d_in[6];
    const float* m1_conv_b = (const float*)d_in[7];
    const float* m1_xproj  = (const float*)d_in[8];
    const float* m1_dt_w   = (const float*)d_in[9];
    const float* m1_dt_b   = (const float*)d_in[10];
    const float* m1_A_log  = (const float*)d_in[11];
    const float* m1_D      = (const float*)d_in[12];
    const float* m1_out_w  = (const float*)d_in[13];
    // d_in[14..22] = m2_* params: x1 branch is exactly zero (series_decomp on
    // a length-1 axis gives res == 0 -> st == 0 -> mamba2(0) == 0).

    float* out = (float*)d_out;
    float* wsf = (float*)d_ws;
    float* W2T = wsf;               // 131072 floats
    float* b2  = wsf + 131072;      // 256 floats

    w2t_all<<<136, 256, 0, stream>>>(lin2_w, lin1_w, lin1_b, lin2_b, W2T, b2);
    fused_h_mamba<<<512, 256, 0, stream>>>(x, W2T, b2, out,
                                           m1_in_w, m1_conv_w, m1_conv_b,
                                           m1_xproj, m1_dt_w, m1_dt_b,
                                           m1_A_log, m1_D, m1_out_w);
}

// Round 3
// 156.436 us; speedup vs baseline: 1.3391x; 1.3391x over previous
//
#include <hip/hip_runtime.h>

// ---------------------------------------------------------------------------
//   x: (32, 512, 128) fp32 -> rows r = b*128 + c, 4096 rows
//   h[r][n2] = sum_l xt[r][l] * W2T[l][n2] + b2[n2],  W2 = lin2_w @ lin1_w
//   out[r][t] = h[r][t] + mamba1(h[r][:])[t]        (x1 branch is exactly 0)
// R9 structure: 2 dispatches.
//   w2t_all  (full-K 32x32 tiles + b2 blocks, 136 blk)
//   fused_h_mamba (512 blk x 256 thr, 2/CU, 8 rows/block):
//     GEMM streams W2T global->register (coalesced 1KB wave-loads, L2-resident,
//     read ONCE per block via 4-way K-split across waves) -- no W2T LDS staging
//     at all.  x-tile (16 KB) in LDS, read as wave-uniform broadcast b128.
//     Cross-wave partial reduce in LDS (one-shot 32 KB), then the verified
//     8-row scan (identical to old mamba_res phases 1-3).
// ---------------------------------------------------------------------------

__device__ __forceinline__ float rcp_f(float x) { return __builtin_amdgcn_rcpf(x); }
__device__ __forceinline__ float silu_f(float x) {
    return x * rcp_f(1.0f + __expf(-x));
}
__device__ __forceinline__ float softplus_f(float x) {
    return fmaxf(x, 0.0f) + __logf(1.0f + __expf(-fabsf(x)));
}

__device__ __forceinline__ unsigned f2_to_h2(float a, float b) {
    _Float16 ha = (_Float16)a, hb = (_Float16)b;
    unsigned short ua = __builtin_bit_cast(unsigned short, ha);
    unsigned short ub = __builtin_bit_cast(unsigned short, hb);
    return (unsigned)ua | ((unsigned)ub << 16);
}
__device__ __forceinline__ float h16_to_f(unsigned u) {
    unsigned short s = (unsigned short)u;
    _Float16 h = __builtin_bit_cast(_Float16, s);
    return (float)h;
}

// DPP row_shr add (rows of 16 lanes); bound_ctrl=1 -> out-of-row reads 0.
#define DPP_ADD(s, ctrl)                                                       \
    (s) += __int_as_float(__builtin_amdgcn_update_dpp(                         \
        0, __float_as_int(s), (ctrl), 0xf, 0xf, true))

// ---------------------------------------------------------------------------
// Kernel A: bid<128: W2T[l*256+n2] = sum_k lin2[n2][k]*lin1[k][l], full K=512,
// 32x32 output tile per block.  bid>=128: b2 = lin2_w@lin1_b + lin2_b.
// ---------------------------------------------------------------------------
__global__ __launch_bounds__(256)
void w2t_all(const float* __restrict__ A,    // lin2_w (256,512) [m][k]
             const float* __restrict__ B,    // lin1_w (512,512) [k][n]
             const float* __restrict__ lin1_b,
             const float* __restrict__ lin2_b,
             float* __restrict__ W2T, float* __restrict__ b2) {
    __shared__ float As[64][34];
    __shared__ float Bs[64][36];
    __shared__ float red[8][33];
    const int tid = threadIdx.x;
    const int bid = blockIdx.x;
    if (bid < 128) {
        const int m0 = (bid & 7) * 32;
        const int n0 = (bid >> 3) * 32;
        const int tr = tid & 15;
        const int tc = tid >> 4;
        const int ma  = tid >> 3;
        const int kqa = tid & 7;
        const int kb  = tid >> 2;
        const int nqb = tid & 3;
        float acc00 = 0.f, acc01 = 0.f, acc10 = 0.f, acc11 = 0.f;

        for (int k0 = 0; k0 < 512; k0 += 64) {
            float4 a0 = *(const float4*)&A[(m0 + ma) * 512 + k0 + kqa * 8];
            float4 a1 = *(const float4*)&A[(m0 + ma) * 512 + k0 + kqa * 8 + 4];
            As[kqa * 8 + 0][ma] = a0.x;
            As[kqa * 8 + 1][ma] = a0.y;
            As[kqa * 8 + 2][ma] = a0.z;
            As[kqa * 8 + 3][ma] = a0.w;
            As[kqa * 8 + 4][ma] = a1.x;
            As[kqa * 8 + 5][ma] = a1.y;
            As[kqa * 8 + 6][ma] = a1.z;
            As[kqa * 8 + 7][ma] = a1.w;
            float4 b0 = *(const float4*)&B[(k0 + kb) * 512 + n0 + nqb * 8];
            float4 b1 = *(const float4*)&B[(k0 + kb) * 512 + n0 + nqb * 8 + 4];
            *(float4*)&Bs[kb][nqb * 8]     = b0;
            *(float4*)&Bs[kb][nqb * 8 + 4] = b1;
            __syncthreads();
#pragma unroll 16
            for (int kk = 0; kk < 64; ++kk) {
                float2 av = *(const float2*)&As[kk][tr * 2];
                float2 bv = *(const float2*)&Bs[kk][tc * 2];
                acc00 = fmaf(av.x, bv.x, acc00);
                acc01 = fmaf(av.x, bv.y, acc01);
                acc10 = fmaf(av.y, bv.x, acc10);
                acc11 = fmaf(av.y, bv.y, acc11);
            }
            __syncthreads();
        }
        const int m = m0 + tr * 2;
        const int nn = n0 + tc * 2;
        W2T[nn * 256 + m]           = acc00;
        W2T[nn * 256 + m + 1]       = acc10;
        W2T[(nn + 1) * 256 + m]     = acc01;
        W2T[(nn + 1) * 256 + m + 1] = acc11;
    } else {
        const int np = tid & 31;
        const int ks = tid >> 5;
        const int n = (bid - 128) * 32 + np;
        float acc = 0.f;
#pragma unroll 16
        for (int k = ks * 64; k < ks * 64 + 64; k += 4) {
            float4 w  = *(const float4*)&A[n * 512 + k];
            float4 bb = *(const float4*)&lin1_b[k];
            acc += w.x * bb.x + w.y * bb.y + w.z * bb.z + w.w * bb.w;
        }
        red[ks][np] = acc;
        __syncthreads();
        if (ks == 0) {
            float s = red[0][np] + red[1][np] + red[2][np] + red[3][np] +
                      red[4][np] + red[5][np] + red[6][np] + red[7][np];
            b2[n] = s + lin2_b[n];
        }
    }
}

// ---------------------------------------------------------------------------
// Kernel B: 512 blocks x 256 threads, 8 rows/block, ~64 KB LDS -> 2 blocks/CU.
//   GEMM: thread (kg = wave 0..3, cc = (tid&63)*4) accumulates
//     acc[r][j] = sum_{l in kg*128..+127} xs[l][r] * W2T[l][cc+j]
//   W2T row loads are lane-consecutive float4 (1 KB/wave-instr, L2-resident,
//   read once per block).  xs reads are wave-uniform broadcast ds_read_b128.
//   Partials reduced across the 4 waves via 32 KB LDS, bias-added into smem2.
//   Scan: byte-identical to the verified 8-row mamba_res (phases 1-3).
//   arrP (16 KB) aliases the dead reduction buffer (32 KB).
// ---------------------------------------------------------------------------
__global__ __launch_bounds__(256, 2)
void fused_h_mamba(const float* __restrict__ x, const float* __restrict__ W2T,
                   const float* __restrict__ b2, float* __restrict__ out,
                   const float* __restrict__ in_w, const float* __restrict__ conv_w,
                   const float* __restrict__ conv_b, const float* __restrict__ xproj,
                   const float* __restrict__ dt_w, const float* __restrict__ dt_b,
                   const float* __restrict__ A_log, const float* __restrict__ Dp,
                   const float* __restrict__ out_w) {
    __shared__ __align__(16) float smem2[8 * 512 + 64];   // 16.6 KB: h, then Sbuf
    __shared__ __align__(16) float xs[512 * 8];           // 16 KB: x-tile [l][r]
    __shared__ __align__(16) char  ubuf[32 * 1024];       // 32 KB: red -> arrP

    float* red  = (float*)ubuf;
    uint2* arrP = (uint2*)ubuf;

    const int tid = threadIdx.x;
    const int bb = (int)blockIdx.x >> 4;
    const int c0 = ((int)blockIdx.x & 15) * 8;

    // phase -1: x-tile -> LDS as xs[l][r]  (r local 0..7)
    {
        const float* xg = x + bb * 65536 + c0;
        const int c  = tid & 7;
        const int l0 = tid >> 3;  // 0..31
#pragma unroll
        for (int q = 0; q < 16; ++q) {
            const int l = l0 + q * 32;
            xs[l * 8 + c] = xg[l * 128 + c];
        }
    }
    __syncthreads();

    // GEMM: K-split across waves, W2T global->reg streamed
    {
        const int kg = tid >> 6;           // wave id 0..3
        const int cq = tid & 63;           // float4 col group
        float acc[8][4];
#pragma unroll
        for (int r = 0; r < 8; ++r)
#pragma unroll
            for (int j = 0; j < 4; ++j) acc[r][j] = 0.f;

        const float4* wbase = (const float4*)(W2T + kg * 128 * 256) + cq;
        const float* xbase = &xs[kg * 128 * 8];

#pragma unroll 4
        for (int l = 0; l < 128; ++l) {
            const float4 wv  = wbase[l * 64];
            const float4 xa0 = *(const float4*)&xbase[l * 8];
            const float4 xa1 = *(const float4*)&xbase[l * 8 + 4];
            acc[0][0] = fmaf(xa0.x, wv.x, acc[0][0]);
            acc[0][1] = fmaf(xa0.x, wv.y, acc[0][1]);
            acc[0][2] = fmaf(xa0.x, wv.z, acc[0][2]);
            acc[0][3] = fmaf(xa0.x, wv.w, acc[0][3]);
            acc[1][0] = fmaf(xa0.y, wv.x, acc[1][0]);
            acc[1][1] = fmaf(xa0.y, wv.y, acc[1][1]);
            acc[1][2] = fmaf(xa0.y, wv.z, acc[1][2]);
            acc[1][3] = fmaf(xa0.y, wv.w, acc[1][3]);
            acc[2][0] = fmaf(xa0.z, wv.x, acc[2][0]);
            acc[2][1] = fmaf(xa0.z, wv.y, acc[2][1]);
            acc[2][2] = fmaf(xa0.z, wv.z, acc[2][2]);
            acc[2][3] = fmaf(xa0.z, wv.w, acc[2][3]);
            acc[3][0] = fmaf(xa0.w, wv.x, acc[3][0]);
            acc[3][1] = fmaf(xa0.w, wv.y, acc[3][1]);
            acc[3][2] = fmaf(xa0.w, wv.z, acc[3][2]);
            acc[3][3] = fmaf(xa0.w, wv.w, acc[3][3]);
            acc[4][0] = fmaf(xa1.x, wv.x, acc[4][0]);
            acc[4][1] = fmaf(xa1.x, wv.y, acc[4][1]);
            acc[4][2] = fmaf(xa1.x, wv.z, acc[4][2]);
            acc[4][3] = fmaf(xa1.x, wv.w, acc[4][3]);
            acc[5][0] = fmaf(xa1.y, wv.x, acc[5][0]);
            acc[5][1] = fmaf(xa1.y, wv.y, acc[5][1]);
            acc[5][2] = fmaf(xa1.y, wv.z, acc[5][2]);
            acc[5][3] = fmaf(xa1.y, wv.w, acc[5][3]);
            acc[6][0] = fmaf(xa1.z, wv.x, acc[6][0]);
            acc[6][1] = fmaf(xa1.z, wv.y, acc[6][1]);
            acc[6][2] = fmaf(xa1.z, wv.z, acc[6][2]);
            acc[6][3] = fmaf(xa1.z, wv.w, acc[6][3]);
            acc[7][0] = fmaf(xa1.w, wv.x, acc[7][0]);
            acc[7][1] = fmaf(xa1.w, wv.y, acc[7][1]);
            acc[7][2] = fmaf(xa1.w, wv.z, acc[7][2]);
            acc[7][3] = fmaf(xa1.w, wv.w, acc[7][3]);
        }
        __syncthreads();  // xs dead (all waves past reads); red may be written
#pragma unroll
        for (int r = 0; r < 8; ++r)
            *(float4*)&red[((kg * 8 + r) << 8) + (cq << 2)] =
                make_float4(acc[r][0], acc[r][1], acc[r][2], acc[r][3]);
    }
    __syncthreads();

    // reduce partials across waves + bias -> h in smem2
    {
        const float4* rp = (const float4*)red;
#pragma unroll
        for (int q = 0; q < 2; ++q) {
            const int idx = tid + q * 256;   // 0..511 = 8 rows x 64 float4
            const int r  = idx >> 6;
            const int c4 = idx & 63;
            float4 s0 = rp[(r)      * 64 + c4];
            float4 s1 = rp[(8 + r)  * 64 + c4];
            float4 s2 = rp[(16 + r) * 64 + c4];
            float4 s3 = rp[(24 + r) * 64 + c4];
            float4 bias = ((const float4*)b2)[c4];
            float4 hv = make_float4(s0.x + s1.x + s2.x + s3.x + bias.x,
                                    s0.y + s1.y + s2.y + s3.y + bias.y,
                                    s0.z + s1.z + s2.z + s3.z + bias.z,
                                    s0.w + s1.w + s2.w + s3.w + bias.w);
            *(float4*)&smem2[r * 256 + (c4 << 2)] = hv;
        }
    }

    // ---------------- mamba1 + residual (verified 8-row structure) ----------
    const int r0 = blockIdx.x * 8;
    const int row  = tid >> 5;   // 0..7
    const int lane = tid & 31;
    const int d    = lane >> 4;
    const int n    = lane & 15;

    const float iw0 = in_w[0], iw1 = in_w[1], iw2 = in_w[2], iw3 = in_w[3];
    const float g00 = iw0 * conv_w[0], g01 = iw0 * conv_w[1];
    const float g02 = iw0 * conv_w[2], g03 = iw0 * conv_w[3];
    const float g10 = iw1 * conv_w[4], g11 = iw1 * conv_w[5];
    const float g12 = iw1 * conv_w[6], g13 = iw1 * conv_w[7];
    const float cb0 = conv_b[0], cb1 = conv_b[1];
    const float xp00 = xproj[0], xp01 = xproj[1];
    const float dtw0 = dt_w[0], dtw1 = dt_w[1];
    const float dtb0 = dt_b[0], dtb1 = dt_b[1];
    const float D0 = Dp[0], D1 = Dp[1];
    const float ow0 = out_w[0], ow1 = out_w[1];

    __syncthreads();  // h visible; red dead -> arrP may be written

    // phase 1: per-t precompute; pack params to 4xfp16; keep w/base in regs
    float w0a[8], w1a[8], basea[8];
#pragma unroll
    for (int j = 0; j < 8; ++j) {
        const int t = lane + 32 * j;
        const float* u = &smem2[row * 256];
        const float u0 = u[t];
        const int i1 = (t >= 1) ? t - 1 : 0;
        const int i2 = (t >= 2) ? t - 2 : 0;
        const int i3 = (t >= 3) ? t - 3 : 0;
        float um1 = u[i1]; um1 = (t >= 1) ? um1 : 0.f;
        float um2 = u[i2]; um2 = (t >= 2) ? um2 : 0.f;
        float um3 = u[i3]; um3 = (t >= 3) ? um3 : 0.f;

        const float p0 = fmaf(g03, u0, fmaf(g02, um1, fmaf(g01, um2, fmaf(g00, um3, cb0))));
        const float p1 = fmaf(g13, u0, fmaf(g12, um1, fmaf(g11, um2, fmaf(g10, um3, cb1))));
        const float xc0 = silu_f(p0);
        const float xc1 = silu_f(p1);
        const float dbc0 = fmaf(xp01, xc1, xp00 * xc0);
        const float dt0 = softplus_f(fmaf(dbc0, dtw0, dtb0));
        const float dt1 = softplus_f(fmaf(dbc0, dtw1, dtb1));
        const float w0 = silu_f(u0 * iw2) * ow0;
        const float w1 = silu_f(u0 * iw3) * ow1;
        w0a[j] = w0;
        w1a[j] = w1;
        basea[j] = fmaf(xc1 * D1, w1, fmaf(xc0 * D0, w0, u0));
        arrP[row * 256 + t] = make_uint2(f2_to_h2(xc0, xc1), f2_to_h2(dt0, dt1));
    }
    __syncthreads();  // arrP ready; smem2 reused as Sbuf (+trash tail)

    // phase 2: sequential scan; lane owns state (d, n)
    const float a_dn = -__expf(A_log[d * 16 + n]);
    const float bn0 = xproj[(1 + n) * 2 + 0];
    const float bn1 = xproj[(1 + n) * 2 + 1];
    const float cn0 = xproj[(17 + n) * 2 + 0];
    const float cn1 = xproj[(17 + n) * 2 + 1];
    const bool is_writer = ((lane & 15) == 15);
    const int dsh = d * 16;  // fp16 select shift for dt_d
    int addr = is_writer ? (row * 512 + d) : (4096 + (tid & 63));
    const int astep = is_writer ? 2 : 0;
    float hstate = 0.f;

#pragma unroll 8
    for (int t = 0; t < 256; ++t) {
        const uint2 P = arrP[row * 256 + t];  // {h2(xc0,xc1), h2(dt0,dt1)}
        const float xc0 = h16_to_f(P.x);
        const float xc1 = h16_to_f(P.x >> 16);
        const float dtd = h16_to_f(P.y >> dsh);
        const float xcd = d ? xc1 : xc0;
        const float bm = fmaf(bn1, xc1, bn0 * xc0);
        const float cm = fmaf(cn1, xc1, cn0 * xc0);
        const float dA = __expf(dtd * a_dn);
        hstate = fmaf(dA, hstate, dtd * xcd * bm);
        float s = hstate * cm;
        DPP_ADD(s, 0x111);  // row_shr:1
        DPP_ADD(s, 0x112);  // row_shr:2
        DPP_ADD(s, 0x114);  // row_shr:4
        DPP_ADD(s, 0x118);  // row_shr:8 -> lane15 of each 16-row has S_d
        smem2[addr] = s;    // unconditional (trash slot for non-writers)
        addr += astep;
    }
    __syncthreads();

    // phase 3: y = base + w0*S0 + w1*S1, coalesced stores
    float* orow = out + (r0 + row) * 256;
#pragma unroll
    for (int j = 0; j < 8; ++j) {
        const int t = lane + 32 * j;
        const float2 S = *(const float2*)&smem2[((row * 256 + t) << 1)];
        orow[t] = fmaf(w1a[j], S.y, fmaf(w0a[j], S.x, basea[j]));
    }
}

// ---------------------------------------------------------------------------
extern "C" void kernel_launch(void* const* d_in, const int* in_sizes, int n_in,
                              void* d_out, int out_size, void* d_ws, size_t ws_size,
                              hipStream_t stream) {
    const float* x      = (const float*)d_in[0];
    const float* lin1_w = (const float*)d_in[1];
    const float* lin1_b = (const float*)d_in[2];
    const float* lin2_w = (const float*)d_in[3];
    const float* lin2_b = (const float*)d_in[4];
    const float* m1_in_w   = (const float*)d_in[5];
    const float* m1_conv_w = (const float*)d_in[6];
    const float* m1_conv_b = (const float*)d_in[7];
    const float* m1_xproj  = (const float*)d_in[8];
    const float* m1_dt_w   = (const float*)d_in[9];
    const float* m1_dt_b   = (const float*)d_in[10];
    const float* m1_A_log  = (const float*)d_in[11];
    const float* m1_D      = (const float*)d_in[12];
    const float* m1_out_w  = (const float*)d_in[13];
    // d_in[14..22] = m2_* params: x1 branch is exactly zero (series_decomp on
    // a length-1 axis gives res == 0 -> st == 0 -> mamba2(0) == 0).

    float* out = (float*)d_out;
    float* wsf = (float*)d_ws;
    float* W2T = wsf;               // 131072 floats
    float* b2  = wsf + 131072;      // 256 floats

    w2t_all<<<136, 256, 0, stream>>>(lin2_w, lin1_w, lin1_b, lin2_b, W2T, b2);
    fused_h_mamba<<<512, 256, 0, stream>>>(x, W2T, b2, out,
                                           m1_in_w, m1_conv_w, m1_conv_b,
                                           m1_xproj, m1_dt_w, m1_dt_b,
                                           m1_A_log, m1_D, m1_out_w);
}